// Round 17
// baseline (202.560 us; speedup 1.0000x reference)
//
#include <hip/hip_runtime.h>

#define NN 50000
#define NE 800000
#define D 64
#define SCAN_B 1024
#define NB ((NN + SCAN_B - 1) / SCAN_B)   // 49 scan blocks
#define TILES 5
#define WAVES 8
#define EPB (16 * TILES * WAVES)           // 640 edges/block (8 waves x 80), grid 1250

typedef __attribute__((ext_vector_type(8))) short bf16x8;
typedef __attribute__((ext_vector_type(4))) float f32x4;
typedef __attribute__((ext_vector_type(4))) unsigned int u32x4;

__device__ __forceinline__ float lrelu(float x) { return x >= 0.0f ? x : 0.2f * x; }

__device__ __forceinline__ unsigned short f2bf(float f) {
    unsigned int x = __float_as_uint(f);
    unsigned int r = (x + 0x7fffu + ((x >> 16) & 1u)) >> 16;   // RNE
    return (unsigned short)r;
}

// wave-local LDS fence (R12/R15-proven): drain my LDS ops, pin scheduler
__device__ __forceinline__ void wave_lds_fence() {
    asm volatile("s_waitcnt lgkmcnt(0)" ::: "memory");
    __builtin_amdgcn_sched_barrier(0);
}

// ---------- fused prep: h->bf16, all 4 weights ->bf16^T, degree count ----------
__global__ __launch_bounds__(256) void prep_count(const float* __restrict__ h,
                                                  unsigned short* __restrict__ hb,
                                                  const int* __restrict__ ei,
                                                  int* __restrict__ counts,
                                                  const float* __restrict__ w1e,
                                                  const float* __restrict__ w2e,
                                                  const float* __restrict__ w1n,
                                                  const float* __restrict__ w2n,
                                                  unsigned short* __restrict__ w1t,
                                                  unsigned short* __restrict__ w2t,
                                                  unsigned short* __restrict__ w1nt,
                                                  unsigned short* __restrict__ w2nt)
{
    int i = blockIdx.x * 256 + threadIdx.x;   // 800000 threads exactly
    float4 v = ((const float4*)h)[i];         // NN*16 == NE exactly
    ushort4 o;
    o.x = f2bf(v.x); o.y = f2bf(v.y); o.z = f2bf(v.z); o.w = f2bf(v.w);
    ((ushort4*)hb)[i] = o;
    atomicAdd(&counts[ei[i]], 1);
    if (i < 8192) {                            // w1t[j][k] = w1e[k][j]
        int j = i >> 7, k = i & 127;
        w1t[i] = f2bf(w1e[k * 64 + j]);
    } else if (i < 12288) {                    // w2t[j][k] = w2e[k][j]
        int t2 = i - 8192;
        int j = t2 >> 6, k = t2 & 63;
        w2t[t2] = f2bf(w2e[k * 64 + j]);
    } else if (i < 20480) {                    // w1nt[j][k] = w1n[k][j]
        int t3 = i - 12288;
        int j = t3 >> 7, k = t3 & 127;
        w1nt[t3] = f2bf(w1n[k * 64 + j]);
    } else if (i < 24576) {                    // w2nt[j][k] = w2n[k][j]
        int t4 = i - 20480;
        int j = t4 >> 6, k = t4 & 63;
        w2nt[t4] = f2bf(w2n[k * 64 + j]);
    }
}

// ---------- CSR build ----------
__global__ __launch_bounds__(SCAN_B) void scan_block_kernel(const int* __restrict__ counts,
                                                            int* __restrict__ offs,
                                                            int* __restrict__ bsums)
{
    int i = blockIdx.x * SCAN_B + threadIdx.x;
    int v = (i < NN) ? counts[i] : 0;
    int lane = threadIdx.x & 63;
    int wid = threadIdx.x >> 6;
    int x = v;
#pragma unroll
    for (int d = 1; d < 64; d <<= 1) {
        int y = __shfl_up(x, d);
        if (lane >= d) x += y;
    }
    __shared__ int wsum[16];
    if (lane == 63) wsum[wid] = x;
    __syncthreads();
    if (wid == 0) {
        int s = (lane < 16) ? wsum[lane] : 0;
#pragma unroll
        for (int d = 1; d < 16; d <<= 1) {
            int y = __shfl_up(s, d);
            if (lane >= d) s += y;
        }
        if (lane < 16) wsum[lane] = s;
    }
    __syncthreads();
    int woff = (wid == 0) ? 0 : wsum[wid - 1];
    int excl = woff + x - v;
    if (i < NN) offs[i] = excl;
    if (threadIdx.x == 0) bsums[blockIdx.x] = wsum[15];
}

__global__ void scan_top_kernel(int* __restrict__ bsums)
{
    if (threadIdx.x == 0 && blockIdx.x == 0) {
        int run = 0;
        for (int b = 0; b < NB; b++) { int t = bsums[b]; bsums[b] = run; run += t; }
    }
}

__global__ __launch_bounds__(SCAN_B) void add_back_kernel(int* __restrict__ offs,
                                                          const int* __restrict__ bsums,
                                                          int* __restrict__ cursor)
{
    int i = blockIdx.x * SCAN_B + threadIdx.x;
    if (i < NN) {
        int o = offs[i] + bsums[blockIdx.x];
        offs[i] = o;
        cursor[i] = o;
    }
}

__global__ __launch_bounds__(256) void scatter_kernel(const int* __restrict__ ei,
                                                      int* __restrict__ cursor,
                                                      int* __restrict__ csr,
                                                      int* __restrict__ rowpos,
                                                      int* __restrict__ colv)
{
    int e = blockIdx.x * 256 + threadIdx.x;
    if (e < NE) {
        int r = ei[e];
        int pos = atomicAdd(&cursor[r], 1);
        csr[pos] = e;
        rowpos[pos] = r;
        colv[pos] = ei[NE + e];
    }
}

// ---------- edge MLP: 8 independent waves/block (R15 base) + setprio + fast-path scan ----------
__global__ __launch_bounds__(512, 2) void egnn_edge_mfma(
    const unsigned short* __restrict__ hb, const float* __restrict__ coord,
    const int* __restrict__ csr, const int* __restrict__ rowpos,
    const int* __restrict__ colv,
    const unsigned short* __restrict__ w1t, const float* __restrict__ b1e,
    const float* __restrict__ w1e,   // fp32, for radial row w1e[128][j]
    const unsigned short* __restrict__ w2t, const float* __restrict__ b2e,
    float* __restrict__ edge_feat, float* __restrict__ agg)
{
    __shared__ unsigned short W1[64 * 128];       // 16 KB, swizzled [j][k]
    __shared__ unsigned short W2[64 * 64];        // 8 KB, swizzled
    __shared__ unsigned short Mb[WAVES][16 * 64]; // 16 KB, 2 KB/wave
    __shared__ float Ob[WAVES][16 * 64];          // 32 KB, 4 KB/wave

    const int t = threadIdx.x;
    // bijective XCD swizzle (m204): nwg = 1250 = 8*156 + 2
    const int orig = blockIdx.x;
    const int xcd = orig & 7, idx8 = orig >> 3;
    const int blk = (xcd < 2 ? xcd * 157 : 2 * 157 + (xcd - 2) * 156) + idx8;

    const int lane = t & 63, wv = t >> 6;
    const int lo = lane & 15, hi = lane >> 4;

    // ---- stage swizzled weights into LDS (once, 512 threads) ----
    for (int c = t; c < 1024; c += 512) {              // W1: 1024 x 16B chunks
        int j = c >> 4, ci = c & 15;
        uint4 v = *(const uint4*)(w1t + j * 128 + ci * 8);
        *(uint4*)((char*)W1 + ((j * 256 + ci * 16) ^ ((j & 7) << 4))) = v;
    }
    for (int c = t; c < 512; c += 512) {               // W2: 512 x 16B chunks
        int j = c >> 3, ci = c & 7;
        uint4 v = *(const uint4*)(w2t + j * 64 + ci * 8);
        *(uint4*)((char*)W2 + ((j * 128 + ci * 16) ^ ((j & 7) << 4))) = v;
    }
    float bj1[4], wl1[4], bj2[4];
#pragma unroll
    for (int ct = 0; ct < 4; ct++) {
        bj1[ct] = b1e[ct * 16 + lo];
        wl1[ct] = w1e[128 * 64 + ct * 16 + lo];
        bj2[ct] = b2e[ct * 16 + lo];
    }
    __syncthreads();                                   // only barrier in the kernel

    char* w1b = (char*)W1;
    char* w2b = (char*)W2;
    char* mb = (char*)Mb[wv];
    char* ob = (char*)Ob[wv];

    const int pbase = blk * EPB + wv * (16 * TILES);

    // ---- ids: every lane holds its edge slot (lane&15) for all 5 tiles ----
    int e5[TILES], row5[TILES], col5[TILES];
    float rad5[TILES];
#pragma unroll
    for (int tl = 0; tl < TILES; tl++) {
        int p = pbase + tl * 16 + lo;     // 4-fold redundant across hi -> same-line coalesce
        e5[tl] = csr[p];
        row5[tl] = rowpos[p];
        col5[tl] = colv[p];
    }
#pragma unroll
    for (int tl = 0; tl < TILES; tl++) {
        float dx = coord[row5[tl] * 3 + 0] - coord[col5[tl] * 3 + 0];
        float dy = coord[row5[tl] * 3 + 1] - coord[col5[tl] * 3 + 1];
        float dz = coord[row5[tl] * 3 + 2] - coord[col5[tl] * 3 + 2];
        rad5[tl] = dx * dx + dy * dy + dz * dz;
    }

    // ---- A-fragment prefetch registers ----
    uint4 aR0, aR1, aC0, aC1, nR0, nR1, nC0, nC1;
    aR0 = *(const uint4*)(hb + (size_t)row5[0] * 64 + hi * 8);
    aR1 = *(const uint4*)(hb + (size_t)row5[0] * 64 + 32 + hi * 8);
    aC0 = *(const uint4*)(hb + (size_t)col5[0] * 64 + hi * 8);
    aC1 = *(const uint4*)(hb + (size_t)col5[0] * 64 + 32 + hi * 8);

#pragma unroll
    for (int tl = 0; tl < TILES; tl++) {
        // issue next tile's A gathers (hidden under this tile's compute)
        if (tl + 1 < TILES) {
            nR0 = *(const uint4*)(hb + (size_t)row5[tl + 1] * 64 + hi * 8);
            nR1 = *(const uint4*)(hb + (size_t)row5[tl + 1] * 64 + 32 + hi * 8);
            nC0 = *(const uint4*)(hb + (size_t)col5[tl + 1] * 64 + hi * 8);
            nC1 = *(const uint4*)(hb + (size_t)col5[tl + 1] * 64 + 32 + hi * 8);
        }

        // ---- layer 1: acc init (bias + radial) then 16 MFMA, B from LDS ----
        float radr[4];
#pragma unroll
        for (int r = 0; r < 4; r++) radr[r] = __shfl(rad5[tl], hi * 4 + r);
        f32x4 acc[4];
#pragma unroll
        for (int ct = 0; ct < 4; ct++)
#pragma unroll
            for (int r = 0; r < 4; r++) acc[ct][r] = fmaf(radr[r], wl1[ct], bj1[ct]);

        bf16x8 af0 = *reinterpret_cast<bf16x8*>(&aR0);
        bf16x8 af1 = *reinterpret_cast<bf16x8*>(&aR1);
        bf16x8 af2 = *reinterpret_cast<bf16x8*>(&aC0);
        bf16x8 af3 = *reinterpret_cast<bf16x8*>(&aC1);
        __builtin_amdgcn_s_setprio(1);
#pragma unroll
        for (int kc = 0; kc < 4; kc++) {
            bf16x8 a = (kc == 0) ? af0 : (kc == 1) ? af1 : (kc == 2) ? af2 : af3;
#pragma unroll
            for (int ct = 0; ct < 4; ct++) {
                bf16x8 b = *(bf16x8*)(w1b + (((ct * 16 + lo) * 256 + kc * 64 + hi * 16) ^ ((lo & 7) << 4)));
                acc[ct] = __builtin_amdgcn_mfma_f32_16x16x32_bf16(a, b, acc[ct], 0, 0, 0);
            }
        }
        __builtin_amdgcn_s_setprio(0);

        // ---- M stage (wave-private), layer 2 ----
#pragma unroll
        for (int ct = 0; ct < 4; ct++)
#pragma unroll
            for (int r = 0; r < 4; r++) {
                int row = hi * 4 + r;
                *(unsigned short*)(mb + ((row * 128 + (ct * 16 + lo) * 2) ^ ((row & 7) << 4))) =
                    f2bf(lrelu(acc[ct][r]));
            }
        wave_lds_fence();

        f32x4 acc2[4];
#pragma unroll
        for (int ct = 0; ct < 4; ct++)
#pragma unroll
            for (int r = 0; r < 4; r++) acc2[ct][r] = bj2[ct];
        __builtin_amdgcn_s_setprio(1);
#pragma unroll
        for (int kc = 0; kc < 2; kc++) {
            bf16x8 a2 = *(bf16x8*)(mb + ((lo * 128 + kc * 64 + hi * 16) ^ ((lo & 7) << 4)));
#pragma unroll
            for (int ct = 0; ct < 4; ct++) {
                bf16x8 b = *(bf16x8*)(w2b + (((ct * 16 + lo) * 128 + kc * 64 + hi * 16) ^ ((lo & 7) << 4)));
                acc2[ct] = __builtin_amdgcn_mfma_f32_16x16x32_bf16(a2, b, acc2[ct], 0, 0, 0);
            }
        }
        __builtin_amdgcn_s_setprio(0);

        // ---- O stage (wave-private fp32), then stores + segmented agg scan ----
#pragma unroll
        for (int ct = 0; ct < 4; ct++)
#pragma unroll
            for (int r = 0; r < 4; r++) {
                int row = hi * 4 + r;
                *(float*)(ob + ((row * 256 + (ct * 16 + lo) * 4) ^ ((row & 7) << 4))) =
                    lrelu(acc2[ct][r]);
            }
        wave_lds_fence();

        // stores: quarter-wave per row, 4 full 256B rows per pass, nontemporal
#pragma unroll
        for (int o = 0; o < 4; o++) {
            int ridx = o * 4 + hi;
            int ee = __shfl(e5[tl], ridx);
            u32x4 v = *(u32x4*)(ob + ((ridx * 256 + lo * 16) ^ ((ridx & 7) << 4)));
            __builtin_nontemporal_store(v, (u32x4*)(edge_feat + (size_t)ee * 64 + lo * 4));
        }
        // segmented agg scan over this wave's 16 sorted pos (lane = column)
        {
            int first = __shfl(row5[tl], 0);
            int last = __shfl(row5[tl], 15);
            if (first == last) {
                // fast path (~40% of windows): whole window one segment -> tree sum
                float v[16];
#pragma unroll
                for (int ii = 0; ii < 16; ii++)
                    v[ii] = *(float*)(ob + ((ii * 256 + lane * 4) ^ ((ii & 7) << 4)));
                float p0 = (v[0] + v[1]) + (v[2] + v[3]);
                float p1 = (v[4] + v[5]) + (v[6] + v[7]);
                float p2 = (v[8] + v[9]) + (v[10] + v[11]);
                float p3 = (v[12] + v[13]) + (v[14] + v[15]);
                atomicAdd(&agg[(size_t)first * 64 + lane], (p0 + p1) + (p2 + p3));
            } else {
                int cur = first;
                float s = *(float*)(ob + ((lane * 4) ^ 0));
#pragma unroll
                for (int ii = 1; ii < 16; ii++) {
                    int r = __shfl(row5[tl], ii);
                    float v = *(float*)(ob + ((ii * 256 + lane * 4) ^ ((ii & 7) << 4)));
                    if (r != cur) {
                        atomicAdd(&agg[(size_t)cur * 64 + lane], s);
                        s = v; cur = r;
                    } else {
                        s += v;
                    }
                }
                atomicAdd(&agg[(size_t)cur * 64 + lane], s);
            }
        }

        aR0 = nR0; aR1 = nR1; aC0 = nC0; aC1 = nC1;
    }
}

// ---------- node MLP (MFMA): streamed agg read, no gather ----------
__global__ __launch_bounds__(256) void agg_node_mfma(
    const unsigned short* __restrict__ hb, const float* __restrict__ h,
    const float* __restrict__ coord, const float* __restrict__ agg,
    const unsigned short* __restrict__ w1nt, const float* __restrict__ b1n,
    const unsigned short* __restrict__ w2nt, const float* __restrict__ b2n,
    float* __restrict__ h_out, float* __restrict__ coord_out)
{
    __shared__ unsigned short Alds[64 * 128];   // [hb | agg_bf16], swizzled
    __shared__ unsigned short Mlds[64 * 64];

    const int t = threadIdx.x, blk = blockIdx.x;
    const int lane = t & 63, wv = t >> 6;
    const int lo = lane & 15, hi = lane >> 4;
    const int nb = blk * 64;
    char* abase = (char*)Alds;
    char* mbase = (char*)Mlds;

    bf16x8 b1f[4], b2f[2];
#pragma unroll
    for (int kc = 0; kc < 4; kc++)
        b1f[kc] = *(const bf16x8*)(w1nt + (wv * 16 + lo) * 128 + kc * 32 + hi * 8);
#pragma unroll
    for (int kc = 0; kc < 2; kc++)
        b2f[kc] = *(const bf16x8*)(w2nt + (wv * 16 + lo) * 64 + kc * 32 + hi * 8);
    const float bj1 = b1n[wv * 16 + lo];
    const float bj2 = b2n[wv * 16 + lo];

    {   // stage hb rows -> A cols 0..63
        int row = t >> 2, seg = t & 3;
        int n = min(nb + row, NN - 1);
        const uint4* src = (const uint4*)(hb + (size_t)n * 64 + seg * 16);
        int base = row * 256 + seg * 32;
        int swr = (row & 7) << 4;
        uint4 v0 = src[0], v1 = src[1];
        *(uint4*)(abase + (base ^ swr)) = v0;
        *(uint4*)(abase + ((base + 16) ^ swr)) = v1;
    }
    {   // stage agg rows (fp32 -> bf16) -> A cols 64..127
        int row = t >> 2, seg = t & 3;
        int n = min(nb + row, NN - 1);
        const float4* asrc = (const float4*)(agg + (size_t)n * 64 + seg * 16);
        float4 a0 = asrc[0], a1 = asrc[1], a2 = asrc[2], a3 = asrc[3];
        unsigned int u0 = f2bf(a0.x) | ((unsigned)f2bf(a0.y) << 16);
        unsigned int u1 = f2bf(a0.z) | ((unsigned)f2bf(a0.w) << 16);
        unsigned int u2 = f2bf(a1.x) | ((unsigned)f2bf(a1.y) << 16);
        unsigned int u3 = f2bf(a1.z) | ((unsigned)f2bf(a1.w) << 16);
        unsigned int u4 = f2bf(a2.x) | ((unsigned)f2bf(a2.y) << 16);
        unsigned int u5 = f2bf(a2.z) | ((unsigned)f2bf(a2.w) << 16);
        unsigned int u6 = f2bf(a3.x) | ((unsigned)f2bf(a3.y) << 16);
        unsigned int u7 = f2bf(a3.z) | ((unsigned)f2bf(a3.w) << 16);
        int base = row * 256 + 128 + seg * 32;
        int swr = (row & 7) << 4;
        *(uint4*)(abase + (base ^ swr)) = make_uint4(u0, u1, u2, u3);
        *(uint4*)(abase + ((base + 16) ^ swr)) = make_uint4(u4, u5, u6, u7);
    }
    __syncthreads();

    f32x4 acc[4];
#pragma unroll
    for (int rt = 0; rt < 4; rt++) {
#pragma unroll
        for (int r = 0; r < 4; r++) acc[rt][r] = bj1;
    }
#pragma unroll
    for (int kc = 0; kc < 4; kc++) {
#pragma unroll
        for (int rt = 0; rt < 4; rt++) {
            int row = rt * 16 + lo;
            bf16x8 a = *(bf16x8*)(abase + ((row * 256 + kc * 64 + hi * 16) ^ ((row & 7) << 4)));
            acc[rt] = __builtin_amdgcn_mfma_f32_16x16x32_bf16(a, b1f[kc], acc[rt], 0, 0, 0);
        }
    }
#pragma unroll
    for (int rt = 0; rt < 4; rt++) {
#pragma unroll
        for (int r = 0; r < 4; r++) {
            int row = rt * 16 + hi * 4 + r;
            *(unsigned short*)(mbase + ((row * 128 + (wv * 16 + lo) * 2) ^ ((row & 7) << 4))) =
                f2bf(lrelu(acc[rt][r]));
        }
    }
    __syncthreads();

    f32x4 acc2[4];
#pragma unroll
    for (int rt = 0; rt < 4; rt++) {
#pragma unroll
        for (int r = 0; r < 4; r++) acc2[rt][r] = bj2;
    }
#pragma unroll
    for (int kc = 0; kc < 2; kc++) {
#pragma unroll
        for (int rt = 0; rt < 4; rt++) {
            int row = rt * 16 + lo;
            bf16x8 a = *(bf16x8*)(mbase + ((row * 128 + kc * 64 + hi * 16) ^ ((row & 7) << 4)));
            acc2[rt] = __builtin_amdgcn_mfma_f32_16x16x32_bf16(a, b2f[kc], acc2[rt], 0, 0, 0);
        }
    }
#pragma unroll
    for (int rt = 0; rt < 4; rt++) {
#pragma unroll
        for (int r = 0; r < 4; r++) {
            int row = rt * 16 + hi * 4 + r;
            int n = nb + row;
            if (n < NN) {
                int c = wv * 16 + lo;
                float v = h[(size_t)n * 64 + c] + acc2[rt][r];
                __builtin_nontemporal_store(v, h_out + (size_t)n * 64 + c);
            }
        }
    }

    if (t < 192) {
        int idx = nb * 3 + t;
        if (idx < NN * 3) coord_out[idx] = coord[idx];
    }
}

extern "C" void kernel_launch(void* const* d_in, const int* in_sizes, int n_in,
                              void* d_out, int out_size, void* d_ws, size_t ws_size,
                              hipStream_t stream)
{
    const float* h     = (const float*)d_in[0];
    const float* coord = (const float*)d_in[1];
    const int*   ei    = (const int*)d_in[2];
    const float* w1e   = (const float*)d_in[3];
    const float* b1e   = (const float*)d_in[4];
    const float* w2e   = (const float*)d_in[5];
    const float* b2e   = (const float*)d_in[6];
    const float* w1n   = (const float*)d_in[7];
    const float* b1n   = (const float*)d_in[8];
    const float* w2n   = (const float*)d_in[9];
    const float* b2n   = (const float*)d_in[10];

    float* out       = (float*)d_out;
    float* h_out     = out;                         // [N, 64]
    float* coord_out = out + (size_t)NN * D;        // [N, 3]
    float* edge_feat = coord_out + (size_t)NN * 3;  // [E, 64]

    char* ws = (char*)d_ws;
    unsigned short* hb   = (unsigned short*)ws;  ws += sizeof(unsigned short) * (size_t)NN * D;  // 6.4 MB
    unsigned short* w1t  = (unsigned short*)ws;  ws += sizeof(unsigned short) * 64 * 128;
    unsigned short* w2t  = (unsigned short*)ws;  ws += sizeof(unsigned short) * 64 * 64;
    unsigned short* w1nt = (unsigned short*)ws;  ws += sizeof(unsigned short) * 64 * 128;
    unsigned short* w2nt = (unsigned short*)ws;  ws += sizeof(unsigned short) * 64 * 64;
    float* agg  = (float*)ws;                    ws += sizeof(float) * (size_t)NN * D;           // 12.8 MB
    int* counts = (int*)ws;                      ws += sizeof(int) * NN;
    int* offs   = (int*)ws;                      ws += sizeof(int) * NN;
    int* cursor = (int*)ws;                      ws += sizeof(int) * NN;
    int* bsums  = (int*)ws;                      ws += sizeof(int) * 64;
    int* csr    = (int*)ws;                      ws += sizeof(int) * NE;                         // 3.2 MB
    int* rowpos = (int*)ws;                      ws += sizeof(int) * NE;                         // 3.2 MB
    int* colv   = (int*)ws;                      ws += sizeof(int) * NE;                         // 3.2 MB

    hipMemsetAsync(counts, 0, sizeof(int) * NN, stream);
    hipMemsetAsync(agg, 0, sizeof(float) * (size_t)NN * D, stream);

    prep_count<<<NE / 256, 256, 0, stream>>>(h, hb, ei, counts,
                                             w1e, w2e, w1n, w2n, w1t, w2t, w1nt, w2nt);

    scan_block_kernel<<<NB, SCAN_B, 0, stream>>>(counts, offs, bsums);
    scan_top_kernel<<<1, 64, 0, stream>>>(bsums);
    add_back_kernel<<<NB, SCAN_B, 0, stream>>>(offs, bsums, cursor);
    scatter_kernel<<<(NE + 255) / 256, 256, 0, stream>>>(ei, cursor, csr, rowpos, colv);

    egnn_edge_mfma<<<NE / EPB, 512, 0, stream>>>(
        hb, coord, csr, rowpos, colv, w1t, b1e, w1e, w2t, b2e, edge_feat, agg);

    agg_node_mfma<<<(NN + 63) / 64, 256, 0, stream>>>(
        hb, h, coord, agg, w1nt, b1n, w2nt, b2n, h_out, coord_out);
}

// Round 18
// 195.886 us; speedup vs baseline: 1.0341x; 1.0341x over previous
//
#include <hip/hip_runtime.h>

#define NN 50000
#define NE 800000
#define D 64
#define SCAN_B 1024
#define NB ((NN + SCAN_B - 1) / SCAN_B)   // 49 scan blocks
#define TILES 5
#define WAVES 8
#define EPB (16 * TILES * WAVES)           // 640 edges/block (8 waves x 80), grid 1250

typedef __attribute__((ext_vector_type(8))) short bf16x8;
typedef __attribute__((ext_vector_type(4))) float f32x4;
typedef __attribute__((ext_vector_type(4))) unsigned int u32x4;

__device__ __forceinline__ float lrelu(float x) { return x >= 0.0f ? x : 0.2f * x; }

__device__ __forceinline__ unsigned short f2bf(float f) {
    unsigned int x = __float_as_uint(f);
    unsigned int r = (x + 0x7fffu + ((x >> 16) & 1u)) >> 16;   // RNE
    return (unsigned short)r;
}

// wave-local LDS fence (R12/R15-proven): drain my LDS ops, pin scheduler
__device__ __forceinline__ void wave_lds_fence() {
    asm volatile("s_waitcnt lgkmcnt(0)" ::: "memory");
    __builtin_amdgcn_sched_barrier(0);
}

// ---------- fused prep: h->bf16, weights->bf16^T, degree count, agg zeroing ----------
__global__ __launch_bounds__(256) void prep_count(const float* __restrict__ h,
                                                  unsigned short* __restrict__ hb,
                                                  const int* __restrict__ ei,
                                                  int* __restrict__ counts,
                                                  const float* __restrict__ w1e,
                                                  const float* __restrict__ w2e,
                                                  const float* __restrict__ w1n,
                                                  const float* __restrict__ w2n,
                                                  unsigned short* __restrict__ w1t,
                                                  unsigned short* __restrict__ w2t,
                                                  unsigned short* __restrict__ w1nt,
                                                  unsigned short* __restrict__ w2nt,
                                                  float* __restrict__ agg)
{
    int i = blockIdx.x * 256 + threadIdx.x;   // 800000 threads exactly
    float4 v = ((const float4*)h)[i];         // NN*16 == NE exactly
    ushort4 o;
    o.x = f2bf(v.x); o.y = f2bf(v.y); o.z = f2bf(v.z); o.w = f2bf(v.w);
    ((ushort4*)hb)[i] = o;
    atomicAdd(&counts[ei[i]], 1);
    // zero agg (3.2M floats == 800000 float4s, coalesced; consumed 2 launches later)
    ((float4*)agg)[i] = make_float4(0.0f, 0.0f, 0.0f, 0.0f);
    if (i < 8192) {                            // w1t[j][k] = w1e[k][j]
        int j = i >> 7, k = i & 127;
        w1t[i] = f2bf(w1e[k * 64 + j]);
    } else if (i < 12288) {                    // w2t[j][k] = w2e[k][j]
        int t2 = i - 8192;
        int j = t2 >> 6, k = t2 & 63;
        w2t[t2] = f2bf(w2e[k * 64 + j]);
    } else if (i < 20480) {                    // w1nt[j][k] = w1n[k][j]
        int t3 = i - 12288;
        int j = t3 >> 7, k = t3 & 127;
        w1nt[t3] = f2bf(w1n[k * 64 + j]);
    } else if (i < 24576) {                    // w2nt[j][k] = w2n[k][j]
        int t4 = i - 20480;
        int j = t4 >> 6, k = t4 & 63;
        w2nt[t4] = f2bf(w2n[k * 64 + j]);
    }
}

// ---------- CSR build ----------
__global__ __launch_bounds__(SCAN_B) void scan_block_kernel(const int* __restrict__ counts,
                                                            int* __restrict__ offs,
                                                            int* __restrict__ bsums)
{
    int i = blockIdx.x * SCAN_B + threadIdx.x;
    int v = (i < NN) ? counts[i] : 0;
    int lane = threadIdx.x & 63;
    int wid = threadIdx.x >> 6;
    int x = v;
#pragma unroll
    for (int d = 1; d < 64; d <<= 1) {
        int y = __shfl_up(x, d);
        if (lane >= d) x += y;
    }
    __shared__ int wsum[16];
    if (lane == 63) wsum[wid] = x;
    __syncthreads();
    if (wid == 0) {
        int s = (lane < 16) ? wsum[lane] : 0;
#pragma unroll
        for (int d = 1; d < 16; d <<= 1) {
            int y = __shfl_up(s, d);
            if (lane >= d) s += y;
        }
        if (lane < 16) wsum[lane] = s;
    }
    __syncthreads();
    int woff = (wid == 0) ? 0 : wsum[wid - 1];
    int excl = woff + x - v;
    if (i < NN) offs[i] = excl;
    if (threadIdx.x == 0) bsums[blockIdx.x] = wsum[15];
}

__global__ void scan_top_kernel(int* __restrict__ bsums)
{
    if (threadIdx.x == 0 && blockIdx.x == 0) {
        int run = 0;
        for (int b = 0; b < NB; b++) { int t = bsums[b]; bsums[b] = run; run += t; }
    }
}

__global__ __launch_bounds__(SCAN_B) void add_back_kernel(int* __restrict__ offs,
                                                          const int* __restrict__ bsums,
                                                          int* __restrict__ cursor)
{
    int i = blockIdx.x * SCAN_B + threadIdx.x;
    if (i < NN) {
        int o = offs[i] + bsums[blockIdx.x];
        offs[i] = o;
        cursor[i] = o;
    }
}

__global__ __launch_bounds__(256) void scatter_kernel(const int* __restrict__ ei,
                                                      int* __restrict__ cursor,
                                                      int* __restrict__ csr,
                                                      int* __restrict__ rowpos,
                                                      int* __restrict__ colv)
{
    int e = blockIdx.x * 256 + threadIdx.x;
    if (e < NE) {
        int r = ei[e];
        int pos = atomicAdd(&cursor[r], 1);
        csr[pos] = e;
        rowpos[pos] = r;
        colv[pos] = ei[NE + e];
    }
}

// ---------- edge MLP: 8 independent waves/block (R15 base) + setprio + fast-path scan ----------
__global__ __launch_bounds__(512, 2) void egnn_edge_mfma(
    const unsigned short* __restrict__ hb, const float* __restrict__ coord,
    const int* __restrict__ csr, const int* __restrict__ rowpos,
    const int* __restrict__ colv,
    const unsigned short* __restrict__ w1t, const float* __restrict__ b1e,
    const float* __restrict__ w1e,   // fp32, for radial row w1e[128][j]
    const unsigned short* __restrict__ w2t, const float* __restrict__ b2e,
    float* __restrict__ edge_feat, float* __restrict__ agg)
{
    __shared__ unsigned short W1[64 * 128];       // 16 KB, swizzled [j][k]
    __shared__ unsigned short W2[64 * 64];        // 8 KB, swizzled
    __shared__ unsigned short Mb[WAVES][16 * 64]; // 16 KB, 2 KB/wave
    __shared__ float Ob[WAVES][16 * 64];          // 32 KB, 4 KB/wave

    const int t = threadIdx.x;
    // bijective XCD swizzle (m204): nwg = 1250 = 8*156 + 2
    const int orig = blockIdx.x;
    const int xcd = orig & 7, idx8 = orig >> 3;
    const int blk = (xcd < 2 ? xcd * 157 : 2 * 157 + (xcd - 2) * 156) + idx8;

    const int lane = t & 63, wv = t >> 6;
    const int lo = lane & 15, hi = lane >> 4;

    // ---- stage swizzled weights into LDS (once, 512 threads) ----
    for (int c = t; c < 1024; c += 512) {              // W1: 1024 x 16B chunks
        int j = c >> 4, ci = c & 15;
        uint4 v = *(const uint4*)(w1t + j * 128 + ci * 8);
        *(uint4*)((char*)W1 + ((j * 256 + ci * 16) ^ ((j & 7) << 4))) = v;
    }
    for (int c = t; c < 512; c += 512) {               // W2: 512 x 16B chunks
        int j = c >> 3, ci = c & 7;
        uint4 v = *(const uint4*)(w2t + j * 64 + ci * 8);
        *(uint4*)((char*)W2 + ((j * 128 + ci * 16) ^ ((j & 7) << 4))) = v;
    }
    float bj1[4], wl1[4], bj2[4];
#pragma unroll
    for (int ct = 0; ct < 4; ct++) {
        bj1[ct] = b1e[ct * 16 + lo];
        wl1[ct] = w1e[128 * 64 + ct * 16 + lo];
        bj2[ct] = b2e[ct * 16 + lo];
    }
    __syncthreads();                                   // only barrier in the kernel

    char* w1b = (char*)W1;
    char* w2b = (char*)W2;
    char* mb = (char*)Mb[wv];
    char* ob = (char*)Ob[wv];

    const int pbase = blk * EPB + wv * (16 * TILES);

    // ---- ids: every lane holds its edge slot (lane&15) for all 5 tiles ----
    int e5[TILES], row5[TILES], col5[TILES];
    float rad5[TILES];
#pragma unroll
    for (int tl = 0; tl < TILES; tl++) {
        int p = pbase + tl * 16 + lo;     // 4-fold redundant across hi -> same-line coalesce
        e5[tl] = csr[p];
        row5[tl] = rowpos[p];
        col5[tl] = colv[p];
    }
#pragma unroll
    for (int tl = 0; tl < TILES; tl++) {
        float dx = coord[row5[tl] * 3 + 0] - coord[col5[tl] * 3 + 0];
        float dy = coord[row5[tl] * 3 + 1] - coord[col5[tl] * 3 + 1];
        float dz = coord[row5[tl] * 3 + 2] - coord[col5[tl] * 3 + 2];
        rad5[tl] = dx * dx + dy * dy + dz * dz;
    }

    // ---- A-fragment prefetch registers ----
    uint4 aR0, aR1, aC0, aC1, nR0, nR1, nC0, nC1;
    aR0 = *(const uint4*)(hb + (size_t)row5[0] * 64 + hi * 8);
    aR1 = *(const uint4*)(hb + (size_t)row5[0] * 64 + 32 + hi * 8);
    aC0 = *(const uint4*)(hb + (size_t)col5[0] * 64 + hi * 8);
    aC1 = *(const uint4*)(hb + (size_t)col5[0] * 64 + 32 + hi * 8);

#pragma unroll
    for (int tl = 0; tl < TILES; tl++) {
        // issue next tile's A gathers (hidden under this tile's compute)
        if (tl + 1 < TILES) {
            nR0 = *(const uint4*)(hb + (size_t)row5[tl + 1] * 64 + hi * 8);
            nR1 = *(const uint4*)(hb + (size_t)row5[tl + 1] * 64 + 32 + hi * 8);
            nC0 = *(const uint4*)(hb + (size_t)col5[tl + 1] * 64 + hi * 8);
            nC1 = *(const uint4*)(hb + (size_t)col5[tl + 1] * 64 + 32 + hi * 8);
        }

        // ---- layer 1: acc init (bias + radial) then 16 MFMA, B from LDS ----
        float radr[4];
#pragma unroll
        for (int r = 0; r < 4; r++) radr[r] = __shfl(rad5[tl], hi * 4 + r);
        f32x4 acc[4];
#pragma unroll
        for (int ct = 0; ct < 4; ct++)
#pragma unroll
            for (int r = 0; r < 4; r++) acc[ct][r] = fmaf(radr[r], wl1[ct], bj1[ct]);

        bf16x8 af0 = *reinterpret_cast<bf16x8*>(&aR0);
        bf16x8 af1 = *reinterpret_cast<bf16x8*>(&aR1);
        bf16x8 af2 = *reinterpret_cast<bf16x8*>(&aC0);
        bf16x8 af3 = *reinterpret_cast<bf16x8*>(&aC1);
        __builtin_amdgcn_s_setprio(1);
#pragma unroll
        for (int kc = 0; kc < 4; kc++) {
            bf16x8 a = (kc == 0) ? af0 : (kc == 1) ? af1 : (kc == 2) ? af2 : af3;
#pragma unroll
            for (int ct = 0; ct < 4; ct++) {
                bf16x8 b = *(bf16x8*)(w1b + (((ct * 16 + lo) * 256 + kc * 64 + hi * 16) ^ ((lo & 7) << 4)));
                acc[ct] = __builtin_amdgcn_mfma_f32_16x16x32_bf16(a, b, acc[ct], 0, 0, 0);
            }
        }
        __builtin_amdgcn_s_setprio(0);

        // ---- M stage (wave-private), layer 2 ----
#pragma unroll
        for (int ct = 0; ct < 4; ct++)
#pragma unroll
            for (int r = 0; r < 4; r++) {
                int row = hi * 4 + r;
                *(unsigned short*)(mb + ((row * 128 + (ct * 16 + lo) * 2) ^ ((row & 7) << 4))) =
                    f2bf(lrelu(acc[ct][r]));
            }
        wave_lds_fence();

        f32x4 acc2[4];
#pragma unroll
        for (int ct = 0; ct < 4; ct++)
#pragma unroll
            for (int r = 0; r < 4; r++) acc2[ct][r] = bj2[ct];
        __builtin_amdgcn_s_setprio(1);
#pragma unroll
        for (int kc = 0; kc < 2; kc++) {
            bf16x8 a2 = *(bf16x8*)(mb + ((lo * 128 + kc * 64 + hi * 16) ^ ((lo & 7) << 4)));
#pragma unroll
            for (int ct = 0; ct < 4; ct++) {
                bf16x8 b = *(bf16x8*)(w2b + (((ct * 16 + lo) * 128 + kc * 64 + hi * 16) ^ ((lo & 7) << 4)));
                acc2[ct] = __builtin_amdgcn_mfma_f32_16x16x32_bf16(a2, b, acc2[ct], 0, 0, 0);
            }
        }
        __builtin_amdgcn_s_setprio(0);

        // ---- O stage (wave-private fp32), then stores + segmented agg scan ----
#pragma unroll
        for (int ct = 0; ct < 4; ct++)
#pragma unroll
            for (int r = 0; r < 4; r++) {
                int row = hi * 4 + r;
                *(float*)(ob + ((row * 256 + (ct * 16 + lo) * 4) ^ ((row & 7) << 4))) =
                    lrelu(acc2[ct][r]);
            }
        wave_lds_fence();

        // stores: quarter-wave per row, 4 full 256B rows per pass, nontemporal
#pragma unroll
        for (int o = 0; o < 4; o++) {
            int ridx = o * 4 + hi;
            int ee = __shfl(e5[tl], ridx);
            u32x4 v = *(u32x4*)(ob + ((ridx * 256 + lo * 16) ^ ((ridx & 7) << 4)));
            __builtin_nontemporal_store(v, (u32x4*)(edge_feat + (size_t)ee * 64 + lo * 4));
        }
        // segmented agg scan over this wave's 16 sorted pos (lane = column)
        {
            int first = __shfl(row5[tl], 0);
            int last = __shfl(row5[tl], 15);
            if (first == last) {
                // fast path (~40% of windows): whole window one segment -> tree sum
                float v[16];
#pragma unroll
                for (int ii = 0; ii < 16; ii++)
                    v[ii] = *(float*)(ob + ((ii * 256 + lane * 4) ^ ((ii & 7) << 4)));
                float p0 = (v[0] + v[1]) + (v[2] + v[3]);
                float p1 = (v[4] + v[5]) + (v[6] + v[7]);
                float p2 = (v[8] + v[9]) + (v[10] + v[11]);
                float p3 = (v[12] + v[13]) + (v[14] + v[15]);
                atomicAdd(&agg[(size_t)first * 64 + lane], (p0 + p1) + (p2 + p3));
            } else {
                int cur = first;
                float s = *(float*)(ob + ((lane * 4) ^ 0));
#pragma unroll
                for (int ii = 1; ii < 16; ii++) {
                    int r = __shfl(row5[tl], ii);
                    float v = *(float*)(ob + ((ii * 256 + lane * 4) ^ ((ii & 7) << 4)));
                    if (r != cur) {
                        atomicAdd(&agg[(size_t)cur * 64 + lane], s);
                        s = v; cur = r;
                    } else {
                        s += v;
                    }
                }
                atomicAdd(&agg[(size_t)cur * 64 + lane], s);
            }
        }

        aR0 = nR0; aR1 = nR1; aC0 = nC0; aC1 = nC1;
    }
}

// ---------- node MLP (MFMA): streamed agg read, no gather ----------
__global__ __launch_bounds__(256) void agg_node_mfma(
    const unsigned short* __restrict__ hb, const float* __restrict__ h,
    const float* __restrict__ coord, const float* __restrict__ agg,
    const unsigned short* __restrict__ w1nt, const float* __restrict__ b1n,
    const unsigned short* __restrict__ w2nt, const float* __restrict__ b2n,
    float* __restrict__ h_out, float* __restrict__ coord_out)
{
    __shared__ unsigned short Alds[64 * 128];   // [hb | agg_bf16], swizzled
    __shared__ unsigned short Mlds[64 * 64];

    const int t = threadIdx.x, blk = blockIdx.x;
    const int lane = t & 63, wv = t >> 6;
    const int lo = lane & 15, hi = lane >> 4;
    const int nb = blk * 64;
    char* abase = (char*)Alds;
    char* mbase = (char*)Mlds;

    bf16x8 b1f[4], b2f[2];
#pragma unroll
    for (int kc = 0; kc < 4; kc++)
        b1f[kc] = *(const bf16x8*)(w1nt + (wv * 16 + lo) * 128 + kc * 32 + hi * 8);
#pragma unroll
    for (int kc = 0; kc < 2; kc++)
        b2f[kc] = *(const bf16x8*)(w2nt + (wv * 16 + lo) * 64 + kc * 32 + hi * 8);
    const float bj1 = b1n[wv * 16 + lo];
    const float bj2 = b2n[wv * 16 + lo];

    {   // stage hb rows -> A cols 0..63
        int row = t >> 2, seg = t & 3;
        int n = min(nb + row, NN - 1);
        const uint4* src = (const uint4*)(hb + (size_t)n * 64 + seg * 16);
        int base = row * 256 + seg * 32;
        int swr = (row & 7) << 4;
        uint4 v0 = src[0], v1 = src[1];
        *(uint4*)(abase + (base ^ swr)) = v0;
        *(uint4*)(abase + ((base + 16) ^ swr)) = v1;
    }
    {   // stage agg rows (fp32 -> bf16) -> A cols 64..127
        int row = t >> 2, seg = t & 3;
        int n = min(nb + row, NN - 1);
        const float4* asrc = (const float4*)(agg + (size_t)n * 64 + seg * 16);
        float4 a0 = asrc[0], a1 = asrc[1], a2 = asrc[2], a3 = asrc[3];
        unsigned int u0 = f2bf(a0.x) | ((unsigned)f2bf(a0.y) << 16);
        unsigned int u1 = f2bf(a0.z) | ((unsigned)f2bf(a0.w) << 16);
        unsigned int u2 = f2bf(a1.x) | ((unsigned)f2bf(a1.y) << 16);
        unsigned int u3 = f2bf(a1.z) | ((unsigned)f2bf(a1.w) << 16);
        unsigned int u4 = f2bf(a2.x) | ((unsigned)f2bf(a2.y) << 16);
        unsigned int u5 = f2bf(a2.z) | ((unsigned)f2bf(a2.w) << 16);
        unsigned int u6 = f2bf(a3.x) | ((unsigned)f2bf(a3.y) << 16);
        unsigned int u7 = f2bf(a3.z) | ((unsigned)f2bf(a3.w) << 16);
        int base = row * 256 + 128 + seg * 32;
        int swr = (row & 7) << 4;
        *(uint4*)(abase + (base ^ swr)) = make_uint4(u0, u1, u2, u3);
        *(uint4*)(abase + ((base + 16) ^ swr)) = make_uint4(u4, u5, u6, u7);
    }
    __syncthreads();

    f32x4 acc[4];
#pragma unroll
    for (int rt = 0; rt < 4; rt++) {
#pragma unroll
        for (int r = 0; r < 4; r++) acc[rt][r] = bj1;
    }
#pragma unroll
    for (int kc = 0; kc < 4; kc++) {
#pragma unroll
        for (int rt = 0; rt < 4; rt++) {
            int row = rt * 16 + lo;
            bf16x8 a = *(bf16x8*)(abase + ((row * 256 + kc * 64 + hi * 16) ^ ((row & 7) << 4)));
            acc[rt] = __builtin_amdgcn_mfma_f32_16x16x32_bf16(a, b1f[kc], acc[rt], 0, 0, 0);
        }
    }
#pragma unroll
    for (int rt = 0; rt < 4; rt++) {
#pragma unroll
        for (int r = 0; r < 4; r++) {
            int row = rt * 16 + hi * 4 + r;
            *(unsigned short*)(mbase + ((row * 128 + (wv * 16 + lo) * 2) ^ ((row & 7) << 4))) =
                f2bf(lrelu(acc[rt][r]));
        }
    }
    __syncthreads();

    f32x4 acc2[4];
#pragma unroll
    for (int rt = 0; rt < 4; rt++) {
#pragma unroll
        for (int r = 0; r < 4; r++) acc2[rt][r] = bj2;
    }
#pragma unroll
    for (int kc = 0; kc < 2; kc++) {
#pragma unroll
        for (int rt = 0; rt < 4; rt++) {
            int row = rt * 16 + lo;
            bf16x8 a = *(bf16x8*)(mbase + ((row * 128 + kc * 64 + hi * 16) ^ ((row & 7) << 4)));
            acc2[rt] = __builtin_amdgcn_mfma_f32_16x16x32_bf16(a, b2f[kc], acc2[rt], 0, 0, 0);
        }
    }
#pragma unroll
    for (int rt = 0; rt < 4; rt++) {
#pragma unroll
        for (int r = 0; r < 4; r++) {
            int row = rt * 16 + hi * 4 + r;
            int n = nb + row;
            if (n < NN) {
                int c = wv * 16 + lo;
                float v = h[(size_t)n * 64 + c] + acc2[rt][r];
                __builtin_nontemporal_store(v, h_out + (size_t)n * 64 + c);
            }
        }
    }

    if (t < 192) {
        int idx = nb * 3 + t;
        if (idx < NN * 3) coord_out[idx] = coord[idx];
    }
}

extern "C" void kernel_launch(void* const* d_in, const int* in_sizes, int n_in,
                              void* d_out, int out_size, void* d_ws, size_t ws_size,
                              hipStream_t stream)
{
    const float* h     = (const float*)d_in[0];
    const float* coord = (const float*)d_in[1];
    const int*   ei    = (const int*)d_in[2];
    const float* w1e   = (const float*)d_in[3];
    const float* b1e   = (const float*)d_in[4];
    const float* w2e   = (const float*)d_in[5];
    const float* b2e   = (const float*)d_in[6];
    const float* w1n   = (const float*)d_in[7];
    const float* b1n   = (const float*)d_in[8];
    const float* w2n   = (const float*)d_in[9];
    const float* b2n   = (const float*)d_in[10];

    float* out       = (float*)d_out;
    float* h_out     = out;                         // [N, 64]
    float* coord_out = out + (size_t)NN * D;        // [N, 3]
    float* edge_feat = coord_out + (size_t)NN * 3;  // [E, 64]

    char* ws = (char*)d_ws;
    unsigned short* hb   = (unsigned short*)ws;  ws += sizeof(unsigned short) * (size_t)NN * D;  // 6.4 MB
    unsigned short* w1t  = (unsigned short*)ws;  ws += sizeof(unsigned short) * 64 * 128;
    unsigned short* w2t  = (unsigned short*)ws;  ws += sizeof(unsigned short) * 64 * 64;
    unsigned short* w1nt = (unsigned short*)ws;  ws += sizeof(unsigned short) * 64 * 128;
    unsigned short* w2nt = (unsigned short*)ws;  ws += sizeof(unsigned short) * 64 * 64;
    float* agg  = (float*)ws;                    ws += sizeof(float) * (size_t)NN * D;           // 12.8 MB
    int* counts = (int*)ws;                      ws += sizeof(int) * NN;
    int* offs   = (int*)ws;                      ws += sizeof(int) * NN;
    int* cursor = (int*)ws;                      ws += sizeof(int) * NN;
    int* bsums  = (int*)ws;                      ws += sizeof(int) * 64;
    int* csr    = (int*)ws;                      ws += sizeof(int) * NE;                         // 3.2 MB
    int* rowpos = (int*)ws;                      ws += sizeof(int) * NE;                         // 3.2 MB
    int* colv   = (int*)ws;                      ws += sizeof(int) * NE;                         // 3.2 MB

    hipMemsetAsync(counts, 0, sizeof(int) * NN, stream);

    prep_count<<<NE / 256, 256, 0, stream>>>(h, hb, ei, counts,
                                             w1e, w2e, w1n, w2n, w1t, w2t, w1nt, w2nt, agg);

    scan_block_kernel<<<NB, SCAN_B, 0, stream>>>(counts, offs, bsums);
    scan_top_kernel<<<1, 64, 0, stream>>>(bsums);
    add_back_kernel<<<NB, SCAN_B, 0, stream>>>(offs, bsums, cursor);
    scatter_kernel<<<(NE + 255) / 256, 256, 0, stream>>>(ei, cursor, csr, rowpos, colv);

    egnn_edge_mfma<<<NE / EPB, 512, 0, stream>>>(
        hb, coord, csr, rowpos, colv, w1t, b1e, w1e, w2t, b2e, edge_feat, agg);

    agg_node_mfma<<<(NN + 63) / 64, 256, 0, stream>>>(
        hb, h, coord, agg, w1nt, b1n, w2nt, b2n, h_out, coord_out);
}

// Round 19
// 195.746 us; speedup vs baseline: 1.0348x; 1.0007x over previous
//
#include <hip/hip_runtime.h>

#define NN 50000
#define NE 800000
#define D 64
#define SCAN_B 1024
#define NB ((NN + SCAN_B - 1) / SCAN_B)   // 49 scan blocks
#define TILES 5
#define WAVES 8
#define EPB (16 * TILES * WAVES)           // 640 edges/block (8 waves x 80), grid 1250

typedef __attribute__((ext_vector_type(8))) short bf16x8;
typedef __attribute__((ext_vector_type(4))) float f32x4;
typedef __attribute__((ext_vector_type(4))) unsigned int u32x4;

__device__ __forceinline__ float lrelu(float x) { return x >= 0.0f ? x : 0.2f * x; }

__device__ __forceinline__ unsigned short f2bf(float f) {
    unsigned int x = __float_as_uint(f);
    unsigned int r = (x + 0x7fffu + ((x >> 16) & 1u)) >> 16;   // RNE
    return (unsigned short)r;
}

// wave-local LDS fence: drain my LDS ops, pin scheduler (kept ONLY at O-stage)
__device__ __forceinline__ void wave_lds_fence() {
    asm volatile("s_waitcnt lgkmcnt(0)" ::: "memory");
    __builtin_amdgcn_sched_barrier(0);
}

// ---------- fused prep: h->bf16, weights->bf16^T, degree count, agg zeroing ----------
__global__ __launch_bounds__(256) void prep_count(const float* __restrict__ h,
                                                  unsigned short* __restrict__ hb,
                                                  const int* __restrict__ ei,
                                                  int* __restrict__ counts,
                                                  const float* __restrict__ w1e,
                                                  const float* __restrict__ w2e,
                                                  const float* __restrict__ w1n,
                                                  const float* __restrict__ w2n,
                                                  unsigned short* __restrict__ w1t,
                                                  unsigned short* __restrict__ w2t,
                                                  unsigned short* __restrict__ w1nt,
                                                  unsigned short* __restrict__ w2nt,
                                                  float* __restrict__ agg)
{
    int i = blockIdx.x * 256 + threadIdx.x;   // 800000 threads exactly
    float4 v = ((const float4*)h)[i];         // NN*16 == NE exactly
    ushort4 o;
    o.x = f2bf(v.x); o.y = f2bf(v.y); o.z = f2bf(v.z); o.w = f2bf(v.w);
    ((ushort4*)hb)[i] = o;
    atomicAdd(&counts[ei[i]], 1);
    ((float4*)agg)[i] = make_float4(0.0f, 0.0f, 0.0f, 0.0f);
    if (i < 8192) {                            // w1t[j][k] = w1e[k][j]
        int j = i >> 7, k = i & 127;
        w1t[i] = f2bf(w1e[k * 64 + j]);
    } else if (i < 12288) {                    // w2t[j][k] = w2e[k][j]
        int t2 = i - 8192;
        int j = t2 >> 6, k = t2 & 63;
        w2t[t2] = f2bf(w2e[k * 64 + j]);
    } else if (i < 20480) {                    // w1nt[j][k] = w1n[k][j]
        int t3 = i - 12288;
        int j = t3 >> 7, k = t3 & 127;
        w1nt[t3] = f2bf(w1n[k * 64 + j]);
    } else if (i < 24576) {                    // w2nt[j][k] = w2n[k][j]
        int t4 = i - 20480;
        int j = t4 >> 6, k = t4 & 63;
        w2nt[t4] = f2bf(w2n[k * 64 + j]);
    }
}

// ---------- CSR build ----------
__global__ __launch_bounds__(SCAN_B) void scan_block_kernel(const int* __restrict__ counts,
                                                            int* __restrict__ offs,
                                                            int* __restrict__ bsums)
{
    int i = blockIdx.x * SCAN_B + threadIdx.x;
    int v = (i < NN) ? counts[i] : 0;
    int lane = threadIdx.x & 63;
    int wid = threadIdx.x >> 6;
    int x = v;
#pragma unroll
    for (int d = 1; d < 64; d <<= 1) {
        int y = __shfl_up(x, d);
        if (lane >= d) x += y;
    }
    __shared__ int wsum[16];
    if (lane == 63) wsum[wid] = x;
    __syncthreads();
    if (wid == 0) {
        int s = (lane < 16) ? wsum[lane] : 0;
#pragma unroll
        for (int d = 1; d < 16; d <<= 1) {
            int y = __shfl_up(s, d);
            if (lane >= d) s += y;
        }
        if (lane < 16) wsum[lane] = s;
    }
    __syncthreads();
    int woff = (wid == 0) ? 0 : wsum[wid - 1];
    int excl = woff + x - v;
    if (i < NN) offs[i] = excl;
    if (threadIdx.x == 0) bsums[blockIdx.x] = wsum[15];
}

__global__ void scan_top_kernel(int* __restrict__ bsums)
{
    if (threadIdx.x == 0 && blockIdx.x == 0) {
        int run = 0;
        for (int b = 0; b < NB; b++) { int t = bsums[b]; bsums[b] = run; run += t; }
    }
}

__global__ __launch_bounds__(SCAN_B) void add_back_kernel(int* __restrict__ offs,
                                                          const int* __restrict__ bsums,
                                                          int* __restrict__ cursor)
{
    int i = blockIdx.x * SCAN_B + threadIdx.x;
    if (i < NN) {
        int o = offs[i] + bsums[blockIdx.x];
        offs[i] = o;
        cursor[i] = o;
    }
}

__global__ __launch_bounds__(256) void scatter_kernel(const int* __restrict__ ei,
                                                      int* __restrict__ cursor,
                                                      int* __restrict__ csr,
                                                      int* __restrict__ rowpos,
                                                      int* __restrict__ colv)
{
    int e = blockIdx.x * 256 + threadIdx.x;
    if (e < NE) {
        int r = ei[e];
        int pos = atomicAdd(&cursor[r], 1);
        csr[pos] = e;
        rowpos[pos] = r;
        colv[pos] = ei[NE + e];
    }
}

// ---------- edge MLP: 8 independent waves/block, setprio, fast-path scan ----------
// R19 change vs R18: NO manual fence between M-write and layer-2 M-read — the
// compiler's LDS alias analysis inserts a fine-grained lgkmcnt(N) (orders only the
// mb accesses) instead of a full drain + sched pin. O-stage fence retained.
__global__ __launch_bounds__(512, 2) void egnn_edge_mfma(
    const unsigned short* __restrict__ hb, const float* __restrict__ coord,
    const int* __restrict__ csr, const int* __restrict__ rowpos,
    const int* __restrict__ colv,
    const unsigned short* __restrict__ w1t, const float* __restrict__ b1e,
    const float* __restrict__ w1e,   // fp32, for radial row w1e[128][j]
    const unsigned short* __restrict__ w2t, const float* __restrict__ b2e,
    float* __restrict__ edge_feat, float* __restrict__ agg)
{
    __shared__ unsigned short W1[64 * 128];       // 16 KB, swizzled [j][k]
    __shared__ unsigned short W2[64 * 64];        // 8 KB, swizzled
    __shared__ unsigned short Mb[WAVES][16 * 64]; // 16 KB, 2 KB/wave
    __shared__ float Ob[WAVES][16 * 64];          // 32 KB, 4 KB/wave

    const int t = threadIdx.x;
    // bijective XCD swizzle (m204): nwg = 1250 = 8*156 + 2
    const int orig = blockIdx.x;
    const int xcd = orig & 7, idx8 = orig >> 3;
    const int blk = (xcd < 2 ? xcd * 157 : 2 * 157 + (xcd - 2) * 156) + idx8;

    const int lane = t & 63, wv = t >> 6;
    const int lo = lane & 15, hi = lane >> 4;

    // ---- stage swizzled weights into LDS (once, 512 threads) ----
    for (int c = t; c < 1024; c += 512) {              // W1: 1024 x 16B chunks
        int j = c >> 4, ci = c & 15;
        uint4 v = *(const uint4*)(w1t + j * 128 + ci * 8);
        *(uint4*)((char*)W1 + ((j * 256 + ci * 16) ^ ((j & 7) << 4))) = v;
    }
    for (int c = t; c < 512; c += 512) {               // W2: 512 x 16B chunks
        int j = c >> 3, ci = c & 7;
        uint4 v = *(const uint4*)(w2t + j * 64 + ci * 8);
        *(uint4*)((char*)W2 + ((j * 128 + ci * 16) ^ ((j & 7) << 4))) = v;
    }
    float bj1[4], wl1[4], bj2[4];
#pragma unroll
    for (int ct = 0; ct < 4; ct++) {
        bj1[ct] = b1e[ct * 16 + lo];
        wl1[ct] = w1e[128 * 64 + ct * 16 + lo];
        bj2[ct] = b2e[ct * 16 + lo];
    }
    __syncthreads();                                   // only barrier in the kernel

    char* w1b = (char*)W1;
    char* w2b = (char*)W2;
    char* mb = (char*)Mb[wv];
    char* ob = (char*)Ob[wv];

    const int pbase = blk * EPB + wv * (16 * TILES);

    // ---- ids: every lane holds its edge slot (lane&15) for all 5 tiles ----
    int e5[TILES], row5[TILES], col5[TILES];
    float rad5[TILES];
#pragma unroll
    for (int tl = 0; tl < TILES; tl++) {
        int p = pbase + tl * 16 + lo;     // 4-fold redundant across hi -> same-line coalesce
        e5[tl] = csr[p];
        row5[tl] = rowpos[p];
        col5[tl] = colv[p];
    }
#pragma unroll
    for (int tl = 0; tl < TILES; tl++) {
        float dx = coord[row5[tl] * 3 + 0] - coord[col5[tl] * 3 + 0];
        float dy = coord[row5[tl] * 3 + 1] - coord[col5[tl] * 3 + 1];
        float dz = coord[row5[tl] * 3 + 2] - coord[col5[tl] * 3 + 2];
        rad5[tl] = dx * dx + dy * dy + dz * dz;
    }

    // ---- A-fragment prefetch registers ----
    uint4 aR0, aR1, aC0, aC1, nR0, nR1, nC0, nC1;
    aR0 = *(const uint4*)(hb + (size_t)row5[0] * 64 + hi * 8);
    aR1 = *(const uint4*)(hb + (size_t)row5[0] * 64 + 32 + hi * 8);
    aC0 = *(const uint4*)(hb + (size_t)col5[0] * 64 + hi * 8);
    aC1 = *(const uint4*)(hb + (size_t)col5[0] * 64 + 32 + hi * 8);

#pragma unroll
    for (int tl = 0; tl < TILES; tl++) {
        // issue next tile's A gathers (hidden under this tile's compute)
        if (tl + 1 < TILES) {
            nR0 = *(const uint4*)(hb + (size_t)row5[tl + 1] * 64 + hi * 8);
            nR1 = *(const uint4*)(hb + (size_t)row5[tl + 1] * 64 + 32 + hi * 8);
            nC0 = *(const uint4*)(hb + (size_t)col5[tl + 1] * 64 + hi * 8);
            nC1 = *(const uint4*)(hb + (size_t)col5[tl + 1] * 64 + 32 + hi * 8);
        }

        // ---- layer 1: acc init (bias + radial) then 16 MFMA, B from LDS ----
        float radr[4];
#pragma unroll
        for (int r = 0; r < 4; r++) radr[r] = __shfl(rad5[tl], hi * 4 + r);
        f32x4 acc[4];
#pragma unroll
        for (int ct = 0; ct < 4; ct++)
#pragma unroll
            for (int r = 0; r < 4; r++) acc[ct][r] = fmaf(radr[r], wl1[ct], bj1[ct]);

        bf16x8 af0 = *reinterpret_cast<bf16x8*>(&aR0);
        bf16x8 af1 = *reinterpret_cast<bf16x8*>(&aR1);
        bf16x8 af2 = *reinterpret_cast<bf16x8*>(&aC0);
        bf16x8 af3 = *reinterpret_cast<bf16x8*>(&aC1);
        __builtin_amdgcn_s_setprio(1);
#pragma unroll
        for (int kc = 0; kc < 4; kc++) {
            bf16x8 a = (kc == 0) ? af0 : (kc == 1) ? af1 : (kc == 2) ? af2 : af3;
#pragma unroll
            for (int ct = 0; ct < 4; ct++) {
                bf16x8 b = *(bf16x8*)(w1b + (((ct * 16 + lo) * 256 + kc * 64 + hi * 16) ^ ((lo & 7) << 4)));
                acc[ct] = __builtin_amdgcn_mfma_f32_16x16x32_bf16(a, b, acc[ct], 0, 0, 0);
            }
        }
        __builtin_amdgcn_s_setprio(0);

        // ---- M stage (wave-private), layer 2 — compiler-ordered (no manual fence) ----
#pragma unroll
        for (int ct = 0; ct < 4; ct++)
#pragma unroll
            for (int r = 0; r < 4; r++) {
                int row = hi * 4 + r;
                *(unsigned short*)(mb + ((row * 128 + (ct * 16 + lo) * 2) ^ ((row & 7) << 4))) =
                    f2bf(lrelu(acc[ct][r]));
            }

        f32x4 acc2[4];
#pragma unroll
        for (int ct = 0; ct < 4; ct++)
#pragma unroll
            for (int r = 0; r < 4; r++) acc2[ct][r] = bj2[ct];
        __builtin_amdgcn_s_setprio(1);
#pragma unroll
        for (int kc = 0; kc < 2; kc++) {
            bf16x8 a2 = *(bf16x8*)(mb + ((lo * 128 + kc * 64 + hi * 16) ^ ((lo & 7) << 4)));
#pragma unroll
            for (int ct = 0; ct < 4; ct++) {
                bf16x8 b = *(bf16x8*)(w2b + (((ct * 16 + lo) * 128 + kc * 64 + hi * 16) ^ ((lo & 7) << 4)));
                acc2[ct] = __builtin_amdgcn_mfma_f32_16x16x32_bf16(a2, b, acc2[ct], 0, 0, 0);
            }
        }
        __builtin_amdgcn_s_setprio(0);

        // ---- O stage (wave-private fp32), then stores + segmented agg scan ----
#pragma unroll
        for (int ct = 0; ct < 4; ct++)
#pragma unroll
            for (int r = 0; r < 4; r++) {
                int row = hi * 4 + r;
                *(float*)(ob + ((row * 256 + (ct * 16 + lo) * 4) ^ ((row & 7) << 4))) =
                    lrelu(acc2[ct][r]);
            }
        wave_lds_fence();

        // stores: quarter-wave per row, 4 full 256B rows per pass, nontemporal
#pragma unroll
        for (int o = 0; o < 4; o++) {
            int ridx = o * 4 + hi;
            int ee = __shfl(e5[tl], ridx);
            u32x4 v = *(u32x4*)(ob + ((ridx * 256 + lo * 16) ^ ((ridx & 7) << 4)));
            __builtin_nontemporal_store(v, (u32x4*)(edge_feat + (size_t)ee * 64 + lo * 4));
        }
        // segmented agg scan over this wave's 16 sorted pos (lane = column)
        {
            int first = __shfl(row5[tl], 0);
            int last = __shfl(row5[tl], 15);
            if (first == last) {
                float v[16];
#pragma unroll
                for (int ii = 0; ii < 16; ii++)
                    v[ii] = *(float*)(ob + ((ii * 256 + lane * 4) ^ ((ii & 7) << 4)));
                float p0 = (v[0] + v[1]) + (v[2] + v[3]);
                float p1 = (v[4] + v[5]) + (v[6] + v[7]);
                float p2 = (v[8] + v[9]) + (v[10] + v[11]);
                float p3 = (v[12] + v[13]) + (v[14] + v[15]);
                atomicAdd(&agg[(size_t)first * 64 + lane], (p0 + p1) + (p2 + p3));
            } else {
                int cur = first;
                float s = *(float*)(ob + ((lane * 4) ^ 0));
#pragma unroll
                for (int ii = 1; ii < 16; ii++) {
                    int r = __shfl(row5[tl], ii);
                    float v = *(float*)(ob + ((ii * 256 + lane * 4) ^ ((ii & 7) << 4)));
                    if (r != cur) {
                        atomicAdd(&agg[(size_t)cur * 64 + lane], s);
                        s = v; cur = r;
                    } else {
                        s += v;
                    }
                }
                atomicAdd(&agg[(size_t)cur * 64 + lane], s);
            }
        }

        aR0 = nR0; aR1 = nR1; aC0 = nC0; aC1 = nC1;
    }
}

// ---------- node MLP (MFMA): streamed agg read, no gather ----------
__global__ __launch_bounds__(256) void agg_node_mfma(
    const unsigned short* __restrict__ hb, const float* __restrict__ h,
    const float* __restrict__ coord, const float* __restrict__ agg,
    const unsigned short* __restrict__ w1nt, const float* __restrict__ b1n,
    const unsigned short* __restrict__ w2nt, const float* __restrict__ b2n,
    float* __restrict__ h_out, float* __restrict__ coord_out)
{
    __shared__ unsigned short Alds[64 * 128];   // [hb | agg_bf16], swizzled
    __shared__ unsigned short Mlds[64 * 64];

    const int t = threadIdx.x, blk = blockIdx.x;
    const int lane = t & 63, wv = t >> 6;
    const int lo = lane & 15, hi = lane >> 4;
    const int nb = blk * 64;
    char* abase = (char*)Alds;
    char* mbase = (char*)Mlds;

    bf16x8 b1f[4], b2f[2];
#pragma unroll
    for (int kc = 0; kc < 4; kc++)
        b1f[kc] = *(const bf16x8*)(w1nt + (wv * 16 + lo) * 128 + kc * 32 + hi * 8);
#pragma unroll
    for (int kc = 0; kc < 2; kc++)
        b2f[kc] = *(const bf16x8*)(w2nt + (wv * 16 + lo) * 64 + kc * 32 + hi * 8);
    const float bj1 = b1n[wv * 16 + lo];
    const float bj2 = b2n[wv * 16 + lo];

    {   // stage hb rows -> A cols 0..63
        int row = t >> 2, seg = t & 3;
        int n = min(nb + row, NN - 1);
        const uint4* src = (const uint4*)(hb + (size_t)n * 64 + seg * 16);
        int base = row * 256 + seg * 32;
        int swr = (row & 7) << 4;
        uint4 v0 = src[0], v1 = src[1];
        *(uint4*)(abase + (base ^ swr)) = v0;
        *(uint4*)(abase + ((base + 16) ^ swr)) = v1;
    }
    {   // stage agg rows (fp32 -> bf16) -> A cols 64..127
        int row = t >> 2, seg = t & 3;
        int n = min(nb + row, NN - 1);
        const float4* asrc = (const float4*)(agg + (size_t)n * 64 + seg * 16);
        float4 a0 = asrc[0], a1 = asrc[1], a2 = asrc[2], a3 = asrc[3];
        unsigned int u0 = f2bf(a0.x) | ((unsigned)f2bf(a0.y) << 16);
        unsigned int u1 = f2bf(a0.z) | ((unsigned)f2bf(a0.w) << 16);
        unsigned int u2 = f2bf(a1.x) | ((unsigned)f2bf(a1.y) << 16);
        unsigned int u3 = f2bf(a1.z) | ((unsigned)f2bf(a1.w) << 16);
        unsigned int u4 = f2bf(a2.x) | ((unsigned)f2bf(a2.y) << 16);
        unsigned int u5 = f2bf(a2.z) | ((unsigned)f2bf(a2.w) << 16);
        unsigned int u6 = f2bf(a3.x) | ((unsigned)f2bf(a3.y) << 16);
        unsigned int u7 = f2bf(a3.z) | ((unsigned)f2bf(a3.w) << 16);
        int base = row * 256 + 128 + seg * 32;
        int swr = (row & 7) << 4;
        *(uint4*)(abase + (base ^ swr)) = make_uint4(u0, u1, u2, u3);
        *(uint4*)(abase + ((base + 16) ^ swr)) = make_uint4(u4, u5, u6, u7);
    }
    __syncthreads();

    f32x4 acc[4];
#pragma unroll
    for (int rt = 0; rt < 4; rt++) {
#pragma unroll
        for (int r = 0; r < 4; r++) acc[rt][r] = bj1;
    }
#pragma unroll
    for (int kc = 0; kc < 4; kc++) {
#pragma unroll
        for (int rt = 0; rt < 4; rt++) {
            int row = rt * 16 + lo;
            bf16x8 a = *(bf16x8*)(abase + ((row * 256 + kc * 64 + hi * 16) ^ ((row & 7) << 4)));
            acc[rt] = __builtin_amdgcn_mfma_f32_16x16x32_bf16(a, b1f[kc], acc[rt], 0, 0, 0);
        }
    }
#pragma unroll
    for (int rt = 0; rt < 4; rt++) {
#pragma unroll
        for (int r = 0; r < 4; r++) {
            int row = rt * 16 + hi * 4 + r;
            *(unsigned short*)(mbase + ((row * 128 + (wv * 16 + lo) * 2) ^ ((row & 7) << 4))) =
                f2bf(lrelu(acc[rt][r]));
        }
    }
    __syncthreads();

    f32x4 acc2[4];
#pragma unroll
    for (int rt = 0; rt < 4; rt++) {
#pragma unroll
        for (int r = 0; r < 4; r++) acc2[rt][r] = bj2;
    }
#pragma unroll
    for (int kc = 0; kc < 2; kc++) {
#pragma unroll
        for (int rt = 0; rt < 4; rt++) {
            int row = rt * 16 + lo;
            bf16x8 a = *(bf16x8*)(mbase + ((row * 128 + kc * 64 + hi * 16) ^ ((row & 7) << 4)));
            acc2[rt] = __builtin_amdgcn_mfma_f32_16x16x32_bf16(a, b2f[kc], acc2[rt], 0, 0, 0);
        }
    }
#pragma unroll
    for (int rt = 0; rt < 4; rt++) {
#pragma unroll
        for (int r = 0; r < 4; r++) {
            int row = rt * 16 + hi * 4 + r;
            int n = nb + row;
            if (n < NN) {
                int c = wv * 16 + lo;
                float v = h[(size_t)n * 64 + c] + acc2[rt][r];
                __builtin_nontemporal_store(v, h_out + (size_t)n * 64 + c);
            }
        }
    }

    if (t < 192) {
        int idx = nb * 3 + t;
        if (idx < NN * 3) coord_out[idx] = coord[idx];
    }
}

extern "C" void kernel_launch(void* const* d_in, const int* in_sizes, int n_in,
                              void* d_out, int out_size, void* d_ws, size_t ws_size,
                              hipStream_t stream)
{
    const float* h     = (const float*)d_in[0];
    const float* coord = (const float*)d_in[1];
    const int*   ei    = (const int*)d_in[2];
    const float* w1e   = (const float*)d_in[3];
    const float* b1e   = (const float*)d_in[4];
    const float* w2e   = (const float*)d_in[5];
    const float* b2e   = (const float*)d_in[6];
    const float* w1n   = (const float*)d_in[7];
    const float* b1n   = (const float*)d_in[8];
    const float* w2n   = (const float*)d_in[9];
    const float* b2n   = (const float*)d_in[10];

    float* out       = (float*)d_out;
    float* h_out     = out;                         // [N, 64]
    float* coord_out = out + (size_t)NN * D;        // [N, 3]
    float* edge_feat = coord_out + (size_t)NN * 3;  // [E, 64]

    char* ws = (char*)d_ws;
    unsigned short* hb   = (unsigned short*)ws;  ws += sizeof(unsigned short) * (size_t)NN * D;  // 6.4 MB
    unsigned short* w1t  = (unsigned short*)ws;  ws += sizeof(unsigned short) * 64 * 128;
    unsigned short* w2t  = (unsigned short*)ws;  ws += sizeof(unsigned short) * 64 * 64;
    unsigned short* w1nt = (unsigned short*)ws;  ws += sizeof(unsigned short) * 64 * 128;
    unsigned short* w2nt = (unsigned short*)ws;  ws += sizeof(unsigned short) * 64 * 64;
    float* agg  = (float*)ws;                    ws += sizeof(float) * (size_t)NN * D;           // 12.8 MB
    int* counts = (int*)ws;                      ws += sizeof(int) * NN;
    int* offs   = (int*)ws;                      ws += sizeof(int) * NN;
    int* cursor = (int*)ws;                      ws += sizeof(int) * NN;
    int* bsums  = (int*)ws;                      ws += sizeof(int) * 64;
    int* csr    = (int*)ws;                      ws += sizeof(int) * NE;                         // 3.2 MB
    int* rowpos = (int*)ws;                      ws += sizeof(int) * NE;                         // 3.2 MB
    int* colv   = (int*)ws;                      ws += sizeof(int) * NE;                         // 3.2 MB

    hipMemsetAsync(counts, 0, sizeof(int) * NN, stream);

    prep_count<<<NE / 256, 256, 0, stream>>>(h, hb, ei, counts,
                                             w1e, w2e, w1n, w2n, w1t, w2t, w1nt, w2nt, agg);

    scan_block_kernel<<<NB, SCAN_B, 0, stream>>>(counts, offs, bsums);
    scan_top_kernel<<<1, 64, 0, stream>>>(bsums);
    add_back_kernel<<<NB, SCAN_B, 0, stream>>>(offs, bsums, cursor);
    scatter_kernel<<<(NE + 255) / 256, 256, 0, stream>>>(ei, cursor, csr, rowpos, colv);

    egnn_edge_mfma<<<NE / EPB, 512, 0, stream>>>(
        hb, coord, csr, rowpos, colv, w1t, b1e, w1e, w2t, b2e, edge_feat, agg);

    agg_node_mfma<<<(NN + 63) / 64, 256, 0, stream>>>(
        hb, h, coord, agg, w1nt, b1n, w2nt, b2n, h_out, coord_out);
}